// Round 11
// baseline (869.807 us; speedup 1.0000x reference)
//
#include <hip/hip_runtime.h>
#include <math.h>

#define H 64
#define VOCABN 64
#define LSEQ 2048
#define LN_EPS 1e-5f

// ---------- generic DPP add helper ----------
template <int CTRL>
__device__ __forceinline__ float dpp_add(float x) {
  return x + __int_as_float(__builtin_amdgcn_update_dpp(
      0, __float_as_int(x), CTRL, 0xF, 0xF, true));
}

// all-lane sum with broadcast result (tables / readout only)
__device__ __forceinline__ float wave_allsum(float x) {
  x = dpp_add<0xB1>(x);   // quad_perm [1,0,3,2]
  x = dpp_add<0x4E>(x);   // quad_perm [2,3,0,1]
  x = dpp_add<0x141>(x);  // row_half_mirror
  x = dpp_add<0x140>(x);  // row_mirror
  x += __shfl_xor(x, 16, 64);
  x += __shfl_xor(x, 32, 64);
  return x;
}

// all-VALU wave64 reduction: lane 63 holds the total (rounds 3/7/8/10 validated)
__device__ __forceinline__ float reduce_to_lane63(float x) {
  x = dpp_add<0x111>(x);  // row_shr:1
  x = dpp_add<0x112>(x);  // row_shr:2
  x = dpp_add<0x114>(x);  // row_shr:4
  x = dpp_add<0x118>(x);  // row_shr:8
  x = dpp_add<0x142>(x);  // row_bcast:15
  x = dpp_add<0x143>(x);  // row_bcast:31
  return x;
}

// ---------------- Kernel A: per-token tables (verbatim rounds 7-10, passed) ----------------
__global__ __launch_bounds__(64) void tables_kernel(
    const float* __restrict__ embed, const float* __restrict__ W1, const float* __restrict__ b1,
    const float* __restrict__ W2, const float* __restrict__ b2,
    const float* __restrict__ ln_g, const float* __restrict__ ln_b,
    const float* __restrict__ Wk, const float* __restrict__ Wv,
    float* __restrict__ Htab, float* __restrict__ Ktab, float* __restrict__ Vtab,
    float* __restrict__ nvtab)
{
  __shared__ float hs[H];
  __shared__ float ff1[2 * H];
  __shared__ float lns[H];
  const int c = blockIdx.x;
  const int i = threadIdx.x;

  float e = embed[c * H + i];
  hs[i] = e;
  __syncthreads();

  float r1 = b1[i], r2 = b1[i + H];
  for (int j = 0; j < H; ++j) {
    float hj = hs[j];
    r1 = fmaf(W1[i * H + j], hj, r1);
    r2 = fmaf(W1[(i + H) * H + j], hj, r2);
  }
  ff1[i]     = fmaxf(r1, 0.f);
  ff1[i + H] = fmaxf(r2, 0.f);
  __syncthreads();

  float o = b2[i];
  for (int m = 0; m < 2 * H; ++m) o = fmaf(W2[i * 2 * H + m], ff1[m], o);
  float y = e + o;

  float mu  = wave_allsum(y) * (1.f / H);
  float d   = y - mu;
  float var = wave_allsum(d * d) * (1.f / H);
  float ln  = d * (1.f / sqrtf(var + LN_EPS)) * ln_g[i] + ln_b[i];
  lns[i] = ln;
  __syncthreads();
  Htab[c * H + i] = ln;

  float k = 0.f, v = 0.f;
  for (int j = 0; j < H; ++j) {
    float lj = lns[j];
    k = fmaf(Wk[i * H + j], lj, k);
    v = fmaf(Wv[i * H + j], lj, v);
  }
  float nk = sqrtf(wave_allsum(k * k));
  Ktab[c * H + i] = k / fmaxf(nk, 1e-12f);
  Vtab[c * H + i] = v;
  float nv = sqrtf(wave_allsum(v * v));
  if (i == 0) nvtab[c] = 0.4f * nv;   // gate threshold, sqrt domain (round-3 semantics)
}

// ---------------- Kernel B: lazy pending-accept residual scan + fused readout ----------------
// One block (4 waves) per batch element. R_base[c][i] in LDS; up to 8 pending accepts
// held in REGISTERS (delta vector = 1 VGPR across lanes; token id uniform). Per step:
// rv = R_base[c] - sum_s G[c_s][c]*d_s (prefetched broadcasts, chronological fma order
// == bitwise identical to round-10's eager RMW). Accept: register append, NO barrier.
// Flush every 8 accepts: one pass over 64 rows (16/wave), 2 barriers per 8 accepts.
// M eager in wave 0 registers only. Gate math verbatim round 10 (sqrt domain).
__global__ __launch_bounds__(256, 1) void scan_kernel(
    const int* __restrict__ x, const float* __restrict__ Htab,
    const float* __restrict__ Ktab, const float* __restrict__ Vtab,
    const float* __restrict__ nvtab,
    const float* __restrict__ Wq, const float* __restrict__ Wr,
    const float* __restrict__ alpha, const float* __restrict__ Wout,
    const float* __restrict__ bout, float* __restrict__ out)
{
  __shared__ float4 Kl4[VOCABN * H / 4];   // khat [c][j]; reused as M_N in readout
  __shared__ float4 Vl4[VOCABN * H / 4];   // v [c][i];   reused as M_T in readout
  __shared__ float4 Gl4[VOCABN * H / 4];   // Gram [c][cc]
  __shared__ float4 Rl4[VOCABN * H / 4];   // residual base [c][i]
  __shared__ int4   xl4[LSEQ / 4];
  __shared__ float  thl[VOCABN];           // 0.4*||v||
  __shared__ float  hbuf[H];
  __shared__ float  qbuf[H];
  __shared__ float  mbuf[H];
  float* Kl = (float*)Kl4;
  float* Vl = (float*)Vl4;
  float* Gl = (float*)Gl4;
  float* Rl = (float*)Rl4;
  int*   xl = (int*)xl4;

  const int b    = blockIdx.x;
  const int tid  = threadIdx.x;
  const int lane = tid & 63;
  const int wid  = tid >> 6;

  // ---- stage tables + token row into LDS (256 threads) ----
  {
    const float4* Kg = (const float4*)Ktab;
    const float4* Vg = (const float4*)Vtab;
    for (int q = tid; q < VOCABN * H / 4; q += 256) {
      float4 vq = Vg[q];
      Kl4[q] = Kg[q]; Vl4[q] = vq; Rl4[q] = vq;   // R init = v (M = 0)
    }
    const int4* xg = (const int4*)(x + b * LSEQ);
    for (int q = tid; q < LSEQ / 4; q += 256) xl4[q] = xg[q];
    if (tid < VOCABN) thl[tid] = nvtab[tid];
  }
  __syncthreads();

  // ---- Gram in LDS, rows split across waves (verbatim round 10) ----
  {
    float4 kr[16];
#pragma unroll
    for (int q = 0; q < 16; ++q) kr[q] = Kl4[lane * 16 + q];
    for (int r = 0; r < 16; ++r) {
      const int c2 = wid * 16 + r;
      const float4* kp2 = (const float4*)(Kl + c2 * H);
      float a0 = 0.f, a1 = 0.f, a2 = 0.f, a3 = 0.f;
#pragma unroll
      for (int q = 0; q < 16; ++q) {
        float4 kq = kp2[q];
        a0 = fmaf(kr[q].x, kq.x, a0);
        a1 = fmaf(kr[q].y, kq.y, a1);
        a2 = fmaf(kr[q].z, kq.z, a2);
        a3 = fmaf(kr[q].w, kq.w, a3);
      }
      Gl[c2 * H + lane] = (a0 + a1) + (a2 + a3);
    }
  }
  __syncthreads();

  float4 M4[16];
#pragma unroll
  for (int q = 0; q < 16; ++q) M4[q] = make_float4(0.f, 0.f, 0.f, 0.f);

  // pending accepts (registers; statically indexed)
  int   p = 0;
  float d0 = 0.f, d1 = 0.f, d2 = 0.f, d3 = 0.f, d4 = 0.f, d5 = 0.f, d6 = 0.f, d7 = 0.f;
  int   s0 = 0,   s1 = 0,   s2 = 0,   s3 = 0,   s4 = 0,   s5 = 0,   s6 = 0,   s7 = 0;
  float g0 = 0.f, g1 = 0.f, g2 = 0.f, g3 = 0.f, g4 = 0.f, g5 = 0.f, g6 = 0.f, g7 = 0.f;

  int   c   = xl[0];
  float thr = thl[c];
  float rvb = Rl[c * H + lane];      // prefetched base residual

  for (int t = 0; t < LSEQ; ++t) {
    const int cn   = (t + 1 < LSEQ) ? xl[t + 1] : 0;
    const float thrn = thl[cn];

    // reconstruct rv (chronological fma order == eager RMW order, bitwise)
    float rv = rvb;
    if (p > 0) {
      rv = fmaf(-g0, d0, rv); rv = fmaf(-g1, d1, rv);
      rv = fmaf(-g2, d2, rv); rv = fmaf(-g3, d3, rv);
      if (p > 4) {
        rv = fmaf(-g4, d4, rv); rv = fmaf(-g5, d5, rv);
        rv = fmaf(-g6, d6, rv); rv = fmaf(-g7, d7, rv);
      }
    }

    float nd2 = reduce_to_lane63(rv * rv);
    float nds = sqrtf(__int_as_float(__builtin_amdgcn_readlane(__float_as_int(nd2), 63)));
    float thu = __int_as_float(__builtin_amdgcn_readfirstlane(__float_as_int(thr)));

    if (nds > thu) {
      // append to pending (uniform p -> static slot assignment; NO LDS, NO barrier)
      if      (p == 0) { d0 = rv; s0 = c; }
      else if (p == 1) { d1 = rv; s1 = c; }
      else if (p == 2) { d2 = rv; s2 = c; }
      else if (p == 3) { d3 = rv; s3 = c; }
      else if (p == 4) { d4 = rv; s4 = c; }
      else if (p == 5) { d5 = rv; s5 = c; }
      else if (p == 6) { d6 = rv; s6 = c; }
      else             { d7 = rv; s7 = c; }
      ++p;

      if (wid == 0) {                      // M eager, wave 0 only
        const float4* kp = (const float4*)(Kl + c * H);
#pragma unroll
        for (int q = 0; q < 16; ++q) {
          float4 k4 = kp[q];
          M4[q].x = fmaf(rv, k4.x, M4[q].x);
          M4[q].y = fmaf(rv, k4.y, M4[q].y);
          M4[q].z = fmaf(rv, k4.z, M4[q].z);
          M4[q].w = fmaf(rv, k4.w, M4[q].w);
        }
      }

      if (p == 8) {                        // flush: apply all 8 to R_base
        __syncthreads();
#pragma unroll
        for (int r = 0; r < 16; ++r) {
          const int cc = wid * 16 + r;
          float val = Rl[cc * H + lane];
          val = fmaf(-Gl[s0 * H + cc], d0, val);
          val = fmaf(-Gl[s1 * H + cc], d1, val);
          val = fmaf(-Gl[s2 * H + cc], d2, val);
          val = fmaf(-Gl[s3 * H + cc], d3, val);
          val = fmaf(-Gl[s4 * H + cc], d4, val);
          val = fmaf(-Gl[s5 * H + cc], d5, val);
          val = fmaf(-Gl[s6 * H + cc], d6, val);
          val = fmaf(-Gl[s7 * H + cc], d7, val);
          Rl[cc * H + lane] = val;
        }
        __syncthreads();
        d0 = d1 = d2 = d3 = d4 = d5 = d6 = d7 = 0.f;
        p = 0;
      }
    }

    // prefetch for next iteration (list is current: append/flush already done)
    rvb = Rl[cn * H + lane];
    if (p > 0) {
      g0 = Gl[s0 * H + cn]; g1 = Gl[s1 * H + cn];
      g2 = Gl[s2 * H + cn]; g3 = Gl[s3 * H + cn];
      if (p > 4) {
        g4 = Gl[s4 * H + cn]; g5 = Gl[s5 * H + cn];
        g6 = Gl[s6 * H + cn]; g7 = Gl[s7 * H + cn];
      }
    }
    c = cn; thr = thrn;
  }

  // ---------------- fused readout: wave 0 only (verbatim round 10, passed) ----------------
  __syncthreads();
  if (wid == 0) {
    float4* MN = (float4*)(Kl + lane * H);
#pragma unroll
    for (int q = 0; q < 16; ++q) MN[q] = M4[q];
#pragma unroll
    for (int q = 0; q < 16; ++q) {
      Vl[(4 * q + 0) * H + lane] = M4[q].x;
      Vl[(4 * q + 1) * H + lane] = M4[q].y;
      Vl[(4 * q + 2) * H + lane] = M4[q].z;
      Vl[(4 * q + 3) * H + lane] = M4[q].w;
    }

    const int clast = xl[LSEQ - 1];
    hbuf[lane] = Htab[clast * H + lane];

    float qi = 0.f;
    for (int j = 0; j < H; ++j) qi = fmaf(Wq[lane * H + j], hbuf[j], qi);
    qbuf[lane] = qi;

    float qri = 0.f;
    for (int j = 0; j < H; ++j) qri = fmaf(Wr[lane * H + j], qbuf[j], qri);

    float n2 = 0.f;
    for (int i2 = 0; i2 < H; ++i2) { float m = Kl[i2 * H + lane]; n2 = fmaf(m, m, n2); }

    const int KS = 8;
    int idxs[KS];
    float nloc = n2;
#pragma unroll
    for (int k = 0; k < KS; ++k) {
      float v = nloc; int idx = lane;
#pragma unroll
      for (int s = 1; s < 64; s <<= 1) {
        float ov = __shfl_xor(v, s, 64);
        int   oi = __shfl_xor(idx, s, 64);
        if (ov > v || (ov == v && oi < idx)) { v = ov; idx = oi; }
      }
      idxs[k] = idx;
      if (lane == idx) nloc = -1.f;
    }

    float sel[KS], lg[KS];
#pragma unroll
    for (int k = 0; k < KS; ++k) {
      float s = Vl[idxs[k] * H + lane];
      sel[k] = s;
      lg[k] = wave_allsum(s * qri) * 0.125f;   // / sqrt(64)
    }
    float lmax = lg[0];
#pragma unroll
    for (int k = 1; k < KS; ++k) lmax = fmaxf(lmax, lg[k]);
    float esum = 0.f, retro = 0.f;
#pragma unroll
    for (int k = 0; k < KS; ++k) {
      float e = expf(lg[k] - lmax);
      esum += e;
      retro = fmaf(e, sel[k], retro);
    }
    retro /= esum;

    float mc = 0.f;
#pragma unroll
    for (int q2 = 0; q2 < 16; ++q2) {
      mc = fmaf(M4[q2].x, qbuf[4 * q2 + 0], mc);
      mc = fmaf(M4[q2].y, qbuf[4 * q2 + 1], mc);
      mc = fmaf(M4[q2].z, qbuf[4 * q2 + 2], mc);
      mc = fmaf(M4[q2].w, qbuf[4 * q2 + 3], mc);
    }

    float a = 1.f / (1.f + expf(-alpha[0]));
    float mixed = fmaxf(fmaf(a, retro, (1.f - a) * mc), 0.f);
    mbuf[lane] = mixed;

    float oo = bout[lane];
    for (int i2 = 0; i2 < H; ++i2) oo = fmaf(Wout[lane * H + i2], mbuf[i2], oo);
    out[b * VOCABN + lane] = oo;
  }
}

extern "C" void kernel_launch(void* const* d_in, const int* in_sizes, int n_in,
                              void* d_out, int out_size, void* d_ws, size_t ws_size,
                              hipStream_t stream) {
  const int*   x     = (const int*)d_in[0];
  const float* embed = (const float*)d_in[1];
  const float* W1    = (const float*)d_in[2];
  const float* b1    = (const float*)d_in[3];
  const float* W2    = (const float*)d_in[4];
  const float* b2    = (const float*)d_in[5];
  const float* ln_g  = (const float*)d_in[6];
  const float* ln_b  = (const float*)d_in[7];
  const float* Wk    = (const float*)d_in[8];
  const float* Wv    = (const float*)d_in[9];
  const float* Wq    = (const float*)d_in[10];
  const float* Wr    = (const float*)d_in[11];
  const float* alpha = (const float*)d_in[12];
  const float* Wout  = (const float*)d_in[13];
  const float* bout  = (const float*)d_in[14];
  float* out = (float*)d_out;

  const int B = in_sizes[0] / LSEQ;

  float* ws    = (float*)d_ws;
  float* Htab  = ws;          // 4096
  float* Ktab  = ws + 4096;   // 4096
  float* Vtab  = ws + 8192;   // 4096
  float* nvtab = ws + 12288;  // 64

  tables_kernel<<<VOCABN, 64, 0, stream>>>(embed, W1, b1, W2, b2, ln_g, ln_b,
                                           Wk, Wv, Htab, Ktab, Vtab, nvtab);
  scan_kernel<<<B, 256, 0, stream>>>(x, Htab, Ktab, Vtab, nvtab,
                                     Wq, Wr, alpha, Wout, bout, out);
}

// Round 12
// 774.989 us; speedup vs baseline: 1.1223x; 1.1223x over previous
//
#include <hip/hip_runtime.h>
#include <math.h>

#define H 64
#define VOCABN 64
#define LSEQ 2048
#define LN_EPS 1e-5f

// ---------- generic DPP add helper ----------
template <int CTRL>
__device__ __forceinline__ float dpp_add(float x) {
  return x + __int_as_float(__builtin_amdgcn_update_dpp(
      0, __float_as_int(x), CTRL, 0xF, 0xF, true));
}

// all-lane sum with broadcast result (tables / readout only)
__device__ __forceinline__ float wave_allsum(float x) {
  x = dpp_add<0xB1>(x);   // quad_perm [1,0,3,2]
  x = dpp_add<0x4E>(x);   // quad_perm [2,3,0,1]
  x = dpp_add<0x141>(x);  // row_half_mirror
  x = dpp_add<0x140>(x);  // row_mirror
  x += __shfl_xor(x, 16, 64);
  x += __shfl_xor(x, 32, 64);
  return x;
}

// all-VALU wave64 reduction: lane 63 holds the total (rounds 3/7/8/10/11 validated)
__device__ __forceinline__ float reduce_to_lane63(float x) {
  x = dpp_add<0x111>(x);  // row_shr:1
  x = dpp_add<0x112>(x);  // row_shr:2
  x = dpp_add<0x114>(x);  // row_shr:4
  x = dpp_add<0x118>(x);  // row_shr:8
  x = dpp_add<0x142>(x);  // row_bcast:15
  x = dpp_add<0x143>(x);  // row_bcast:31
  return x;
}

// ---------------- Kernel A: per-token tables (verbatim rounds 7-11, passed) ----------------
__global__ __launch_bounds__(64) void tables_kernel(
    const float* __restrict__ embed, const float* __restrict__ W1, const float* __restrict__ b1,
    const float* __restrict__ W2, const float* __restrict__ b2,
    const float* __restrict__ ln_g, const float* __restrict__ ln_b,
    const float* __restrict__ Wk, const float* __restrict__ Wv,
    float* __restrict__ Htab, float* __restrict__ Ktab, float* __restrict__ Vtab,
    float* __restrict__ nvtab)
{
  __shared__ float hs[H];
  __shared__ float ff1[2 * H];
  __shared__ float lns[H];
  const int c = blockIdx.x;
  const int i = threadIdx.x;

  float e = embed[c * H + i];
  hs[i] = e;
  __syncthreads();

  float r1 = b1[i], r2 = b1[i + H];
  for (int j = 0; j < H; ++j) {
    float hj = hs[j];
    r1 = fmaf(W1[i * H + j], hj, r1);
    r2 = fmaf(W1[(i + H) * H + j], hj, r2);
  }
  ff1[i]     = fmaxf(r1, 0.f);
  ff1[i + H] = fmaxf(r2, 0.f);
  __syncthreads();

  float o = b2[i];
  for (int m = 0; m < 2 * H; ++m) o = fmaf(W2[i * 2 * H + m], ff1[m], o);
  float y = e + o;

  float mu  = wave_allsum(y) * (1.f / H);
  float d   = y - mu;
  float var = wave_allsum(d * d) * (1.f / H);
  float ln  = d * (1.f / sqrtf(var + LN_EPS)) * ln_g[i] + ln_b[i];
  lns[i] = ln;
  __syncthreads();
  Htab[c * H + i] = ln;

  float k = 0.f, v = 0.f;
  for (int j = 0; j < H; ++j) {
    float lj = lns[j];
    k = fmaf(Wk[i * H + j], lj, k);
    v = fmaf(Wv[i * H + j], lj, v);
  }
  float nk = sqrtf(wave_allsum(k * k));
  Ktab[c * H + i] = k / fmaxf(nk, 1e-12f);
  Vtab[c * H + i] = v;
  float nv = sqrtf(wave_allsum(v * v));
  if (i == 0) nvtab[c] = 0.4f * nv;   // gate threshold, sqrt domain
}

// ---------------- Kernel B: lazy scan, column-split M, depth-2 pipeline ----------------
// One block (4 waves) per batch element. R_base in LDS; <=8 pending accepts in
// registers (chronological fma order == eager RMW order, bitwise; round-11-proven).
// M column-partitioned: wave w owns M[:, 16w..16w+15] (16 FMA/accept, balanced).
// Flush per 8 accepts (2 barriers per 8 accepts). Gate math verbatim (sqrt domain).
__global__ __launch_bounds__(256, 1) void scan_kernel(
    const int* __restrict__ x, const float* __restrict__ Htab,
    const float* __restrict__ Ktab, const float* __restrict__ Vtab,
    const float* __restrict__ nvtab,
    const float* __restrict__ Wq, const float* __restrict__ Wr,
    const float* __restrict__ alpha, const float* __restrict__ Wout,
    const float* __restrict__ bout, float* __restrict__ out)
{
  __shared__ float4 Kl4[VOCABN * H / 4];   // khat [c][j]; becomes M_N after scan
  __shared__ float4 Vl4[VOCABN * H / 4];   // v [c][i];   becomes M_T after scan
  __shared__ float4 Gl4[VOCABN * H / 4];   // Gram [c][cc]
  __shared__ float4 Rl4[VOCABN * H / 4];   // residual base [c][i]
  __shared__ int4   xl4[LSEQ / 4];
  __shared__ float  thl[VOCABN];           // 0.4*||v||
  __shared__ float  hbuf[H];
  __shared__ float  qbuf[H];
  __shared__ float  mbuf[H];
  float* Kl = (float*)Kl4;
  float* Vl = (float*)Vl4;
  float* Gl = (float*)Gl4;
  float* Rl = (float*)Rl4;
  int*   xl = (int*)xl4;

  const int b    = blockIdx.x;
  const int tid  = threadIdx.x;
  const int lane = tid & 63;
  const int wid  = tid >> 6;

  // ---- stage tables + token row into LDS (256 threads) ----
  {
    const float4* Kg = (const float4*)Ktab;
    const float4* Vg = (const float4*)Vtab;
    for (int q = tid; q < VOCABN * H / 4; q += 256) {
      float4 vq = Vg[q];
      Kl4[q] = Kg[q]; Vl4[q] = vq; Rl4[q] = vq;   // R init = v (M = 0)
    }
    const int4* xg = (const int4*)(x + b * LSEQ);
    for (int q = tid; q < LSEQ / 4; q += 256) xl4[q] = xg[q];
    if (tid < VOCABN) thl[tid] = nvtab[tid];
  }
  __syncthreads();

  // ---- Gram in LDS, rows split across waves (verbatim rounds 10/11) ----
  {
    float4 kr[16];
#pragma unroll
    for (int q = 0; q < 16; ++q) kr[q] = Kl4[lane * 16 + q];
    for (int r = 0; r < 16; ++r) {
      const int c2 = wid * 16 + r;
      const float4* kp2 = (const float4*)(Kl + c2 * H);
      float a0 = 0.f, a1 = 0.f, a2 = 0.f, a3 = 0.f;
#pragma unroll
      for (int q = 0; q < 16; ++q) {
        float4 kq = kp2[q];
        a0 = fmaf(kr[q].x, kq.x, a0);
        a1 = fmaf(kr[q].y, kq.y, a1);
        a2 = fmaf(kr[q].z, kq.z, a2);
        a3 = fmaf(kr[q].w, kq.w, a3);
      }
      Gl[c2 * H + lane] = (a0 + a1) + (a2 + a3);
    }
  }
  __syncthreads();

  // M column slice: Mw[r] holds M[lane][wid*16 + 4r .. 4r+3]
  float4 Mw[4];
#pragma unroll
  for (int q = 0; q < 4; ++q) Mw[q] = make_float4(0.f, 0.f, 0.f, 0.f);

  // pending accepts (statically indexed registers)
  int   p = 0;
  float d0 = 0.f, d1 = 0.f, d2 = 0.f, d3 = 0.f, d4 = 0.f, d5 = 0.f, d6 = 0.f, d7 = 0.f;
  int   s0 = 0,   s1 = 0,   s2 = 0,   s3 = 0,   s4 = 0,   s5 = 0,   s6 = 0,   s7 = 0;
  float g0 = 0.f, g1 = 0.f, g2 = 0.f, g3 = 0.f, g4 = 0.f, g5 = 0.f, g6 = 0.f, g7 = 0.f;

  // depth-2 pipeline state
  int   c0 = xl[0], c1 = xl[1];
  float rb0 = Rl[c0 * H + lane];
  float rb1 = Rl[c1 * H + lane];
  float t0 = thl[c0], t1 = thl[c1];

  for (int t = 0; t < LSEQ; ++t) {
    const int ix2 = (t + 2 < LSEQ) ? t + 2 : LSEQ - 1;
    int   c2  = xl[ix2];
    float rb2 = Rl[c2 * H + lane];
    float t2v = thl[c2];

    // reconstruct rv: chronological fma chain (d=0 slots are exact no-ops)
    float rv = rb0;
    if (p > 0) {
      rv = fmaf(-g0, d0, rv); rv = fmaf(-g1, d1, rv);
      rv = fmaf(-g2, d2, rv); rv = fmaf(-g3, d3, rv);
      rv = fmaf(-g4, d4, rv); rv = fmaf(-g5, d5, rv);
      rv = fmaf(-g6, d6, rv); rv = fmaf(-g7, d7, rv);
    }

    float nd2 = reduce_to_lane63(rv * rv);
    float nds = sqrtf(__int_as_float(__builtin_amdgcn_readlane(__float_as_int(nd2), 63)));
    float thu = __int_as_float(__builtin_amdgcn_readfirstlane(__float_as_int(t0)));

    if (nds > thu) {
      // M slice update (balanced: 16 FMA + 4 broadcast b128 per wave)
      const float4* kp = ((const float4*)(Kl + c0 * H)) + wid * 4;
#pragma unroll
      for (int q = 0; q < 4; ++q) {
        float4 k4 = kp[q];
        Mw[q].x = fmaf(rv, k4.x, Mw[q].x);
        Mw[q].y = fmaf(rv, k4.y, Mw[q].y);
        Mw[q].z = fmaf(rv, k4.z, Mw[q].z);
        Mw[q].w = fmaf(rv, k4.w, Mw[q].w);
      }
      // append (uniform p -> static slot)
      if      (p == 0) { d0 = rv; s0 = c0; }
      else if (p == 1) { d1 = rv; s1 = c0; }
      else if (p == 2) { d2 = rv; s2 = c0; }
      else if (p == 3) { d3 = rv; s3 = c0; }
      else if (p == 4) { d4 = rv; s4 = c0; }
      else if (p == 5) { d5 = rv; s5 = c0; }
      else if (p == 6) { d6 = rv; s6 = c0; }
      else             { d7 = rv; s7 = c0; }
      ++p;

      if (p == 8) {                        // flush all 8 into R_base
        __syncthreads();
#pragma unroll
        for (int r = 0; r < 16; ++r) {
          const int cc = wid * 16 + r;
          float val = Rl[cc * H + lane];
          val = fmaf(-Gl[s0 * H + cc], d0, val);
          val = fmaf(-Gl[s1 * H + cc], d1, val);
          val = fmaf(-Gl[s2 * H + cc], d2, val);
          val = fmaf(-Gl[s3 * H + cc], d3, val);
          val = fmaf(-Gl[s4 * H + cc], d4, val);
          val = fmaf(-Gl[s5 * H + cc], d5, val);
          val = fmaf(-Gl[s6 * H + cc], d6, val);
          val = fmaf(-Gl[s7 * H + cc], d7, val);
          Rl[cc * H + lane] = val;
        }
        __syncthreads();
        d0 = d1 = d2 = d3 = d4 = d5 = d6 = d7 = 0.f;
        p = 0;
        rb1 = Rl[c1 * H + lane];           // in-flight bases stale: reload
        rb2 = Rl[c2 * H + lane];
      }
    }

    // g-prefetch for next step's token (post-append list; d=0 slots harmless)
    if (p > 0) {
      g0 = Gl[s0 * H + c1]; g1 = Gl[s1 * H + c1];
      g2 = Gl[s2 * H + c1]; g3 = Gl[s3 * H + c1];
      g4 = Gl[s4 * H + c1]; g5 = Gl[s5 * H + c1];
      g6 = Gl[s6 * H + c1]; g7 = Gl[s7 * H + c1];
    }

    c0 = c1; c1 = c2; rb0 = rb1; rb1 = rb2; t0 = t1; t1 = t2v;
  }

  // ---- reassemble M into LDS: Vl = M_T (conflict-free), Kl = M_N (one-time conflicts) ----
  __syncthreads();
#pragma unroll
  for (int r = 0; r < 4; ++r) {
    const int jb = wid * 16 + r * 4;
    float4 m = Mw[r];
    Vl[(jb + 0) * H + lane] = m.x;
    Vl[(jb + 1) * H + lane] = m.y;
    Vl[(jb + 2) * H + lane] = m.z;
    Vl[(jb + 3) * H + lane] = m.w;
    Kl[lane * H + jb + 0] = m.x;
    Kl[lane * H + jb + 1] = m.y;
    Kl[lane * H + jb + 2] = m.z;
    Kl[lane * H + jb + 3] = m.w;
  }
  __syncthreads();

  // ---------------- fused readout: wave 0 (M from LDS) ----------------
  if (wid == 0) {
    const int clast = xl[LSEQ - 1];
    hbuf[lane] = Htab[clast * H + lane];

    float qi = 0.f;
    for (int j = 0; j < H; ++j) qi = fmaf(Wq[lane * H + j], hbuf[j], qi);
    qbuf[lane] = qi;

    float qri = 0.f;
    for (int j = 0; j < H; ++j) qri = fmaf(Wr[lane * H + j], qbuf[j], qri);

    // slot norms^2: lane s reads M_N column s (conflict-free)
    float n2 = 0.f;
    for (int i2 = 0; i2 < H; ++i2) { float m = Kl[i2 * H + lane]; n2 = fmaf(m, m, n2); }

    // top-8 slots by norm (ties -> smaller index)
    const int KS = 8;
    int idxs[KS];
    float nloc = n2;
#pragma unroll
    for (int k = 0; k < KS; ++k) {
      float v = nloc; int idx = lane;
#pragma unroll
      for (int s = 1; s < 64; s <<= 1) {
        float ov = __shfl_xor(v, s, 64);
        int   oi = __shfl_xor(idx, s, 64);
        if (ov > v || (ov == v && oi < idx)) { v = ov; idx = oi; }
      }
      idxs[k] = idx;
      if (lane == idx) nloc = -1.f;
    }

    float sel[KS], lg[KS];
#pragma unroll
    for (int k = 0; k < KS; ++k) {
      float s = Vl[idxs[k] * H + lane];     // M_T[idx][lane]
      sel[k] = s;
      lg[k] = wave_allsum(s * qri) * 0.125f;   // / sqrt(64)
    }
    float lmax = lg[0];
#pragma unroll
    for (int k = 1; k < KS; ++k) lmax = fmaxf(lmax, lg[k]);
    float esum = 0.f, retro = 0.f;
#pragma unroll
    for (int k = 0; k < KS; ++k) {
      float e = expf(lg[k] - lmax);
      esum += e;
      retro = fmaf(e, sel[k], retro);
    }
    retro /= esum;

    // m_ctx = M q : lane i, ascending j reading M_T[j][lane] (conflict-free)
    float mc = 0.f;
    for (int j = 0; j < H; ++j) mc = fmaf(Vl[j * H + lane], qbuf[j], mc);

    float a = 1.f / (1.f + expf(-alpha[0]));
    float mixed = fmaxf(fmaf(a, retro, (1.f - a) * mc), 0.f);
    mbuf[lane] = mixed;

    float oo = bout[lane];
    for (int i2 = 0; i2 < H; ++i2) oo = fmaf(Wout[lane * H + i2], mbuf[i2], oo);
    out[b * VOCABN + lane] = oo;
  }
}

extern "C" void kernel_launch(void* const* d_in, const int* in_sizes, int n_in,
                              void* d_out, int out_size, void* d_ws, size_t ws_size,
                              hipStream_t stream) {
  const int*   x     = (const int*)d_in[0];
  const float* embed = (const float*)d_in[1];
  const float* W1    = (const float*)d_in[2];
  const float* b1    = (const float*)d_in[3];
  const float* W2    = (const float*)d_in[4];
  const float* b2    = (const float*)d_in[5];
  const float* ln_g  = (const float*)d_in[6];
  const float* ln_b  = (const float*)d_in[7];
  const float* Wk    = (const float*)d_in[8];
  const float* Wv    = (const float*)d_in[9];
  const float* Wq    = (const float*)d_in[10];
  const float* Wr    = (const float*)d_in[11];
  const float* alpha = (const float*)d_in[12];
  const float* Wout  = (const float*)d_in[13];
  const float* bout  = (const float*)d_in[14];
  float* out = (float*)d_out;

  const int B = in_sizes[0] / LSEQ;

  float* ws    = (float*)d_ws;
  float* Htab  = ws;          // 4096
  float* Ktab  = ws + 4096;   // 4096
  float* Vtab  = ws + 8192;   // 4096
  float* nvtab = ws + 12288;  // 64

  tables_kernel<<<VOCABN, 64, 0, stream>>>(embed, W1, b1, W2, b2, ln_g, ln_b,
                                           Wk, Wv, Htab, Ktab, Vtab, nvtab);
  scan_kernel<<<B, 256, 0, stream>>>(x, Htab, Ktab, Vtab, nvtab,
                                     Wq, Wr, alpha, Wout, bout, out);
}

// Round 13
// 561.916 us; speedup vs baseline: 1.5479x; 1.3792x over previous
//
#include <hip/hip_runtime.h>
#include <math.h>

#define H 64
#define VOCABN 64
#define LSEQ 2048
#define LN_EPS 1e-5f

// ---------- generic DPP add helper ----------
template <int CTRL>
__device__ __forceinline__ float dpp_add(float x) {
  return x + __int_as_float(__builtin_amdgcn_update_dpp(
      0, __float_as_int(x), CTRL, 0xF, 0xF, true));
}

// all-lane sum with broadcast result (tables / readout only)
__device__ __forceinline__ float wave_allsum(float x) {
  x = dpp_add<0xB1>(x);   // quad_perm [1,0,3,2]
  x = dpp_add<0x4E>(x);   // quad_perm [2,3,0,1]
  x = dpp_add<0x141>(x);  // row_half_mirror
  x = dpp_add<0x140>(x);  // row_mirror
  x += __shfl_xor(x, 16, 64);
  x += __shfl_xor(x, 32, 64);
  return x;
}

// all-VALU wave64 reduction: lane 63 holds the total (rounds 3/7/8/10/12 validated)
__device__ __forceinline__ float reduce_to_lane63(float x) {
  x = dpp_add<0x111>(x);  // row_shr:1
  x = dpp_add<0x112>(x);  // row_shr:2
  x = dpp_add<0x114>(x);  // row_shr:4
  x = dpp_add<0x118>(x);  // row_shr:8
  x = dpp_add<0x142>(x);  // row_bcast:15
  x = dpp_add<0x143>(x);  // row_bcast:31
  return x;
}

// ---------------- Kernel A: per-token tables (verbatim rounds 7-12, passed) ----------------
__global__ __launch_bounds__(64) void tables_kernel(
    const float* __restrict__ embed, const float* __restrict__ W1, const float* __restrict__ b1,
    const float* __restrict__ W2, const float* __restrict__ b2,
    const float* __restrict__ ln_g, const float* __restrict__ ln_b,
    const float* __restrict__ Wk, const float* __restrict__ Wv,
    float* __restrict__ Htab, float* __restrict__ Ktab, float* __restrict__ Vtab,
    float* __restrict__ nvtab)
{
  __shared__ float hs[H];
  __shared__ float ff1[2 * H];
  __shared__ float lns[H];
  const int c = blockIdx.x;
  const int i = threadIdx.x;

  float e = embed[c * H + i];
  hs[i] = e;
  __syncthreads();

  float r1 = b1[i], r2 = b1[i + H];
  for (int j = 0; j < H; ++j) {
    float hj = hs[j];
    r1 = fmaf(W1[i * H + j], hj, r1);
    r2 = fmaf(W1[(i + H) * H + j], hj, r2);
  }
  ff1[i]     = fmaxf(r1, 0.f);
  ff1[i + H] = fmaxf(r2, 0.f);
  __syncthreads();

  float o = b2[i];
  for (int m = 0; m < 2 * H; ++m) o = fmaf(W2[i * 2 * H + m], ff1[m], o);
  float y = e + o;

  float mu  = wave_allsum(y) * (1.f / H);
  float d   = y - mu;
  float var = wave_allsum(d * d) * (1.f / H);
  float ln  = d * (1.f / sqrtf(var + LN_EPS)) * ln_g[i] + ln_b[i];
  lns[i] = ln;
  __syncthreads();
  Htab[c * H + i] = ln;

  float k = 0.f, v = 0.f;
  for (int j = 0; j < H; ++j) {
    float lj = lns[j];
    k = fmaf(Wk[i * H + j], lj, k);
    v = fmaf(Wv[i * H + j], lj, v);
  }
  float nk = sqrtf(wave_allsum(k * k));
  Ktab[c * H + i] = k / fmaxf(nk, 1e-12f);
  Vtab[c * H + i] = v;
  float nv = sqrtf(wave_allsum(v * v));
  if (i == 0) nvtab[c] = 0.4f * nv;   // gate threshold, sqrt domain
}

// ---------------- Kernel B: eager scan, in-register forwarding, column-split M ----------------
// One block (4 waves) per batch element. R in LDS (eager, round-10 structure).
// Accept: forward next residuals IN-REGISTER (rvn/rb2 fmaf == bitwise the LDS RMW value;
// removes the post-barrier reload latency), RMW 16 rows/wave with b128 G-row reads,
// M column-split 16 FMA/wave (round-12 reassembly+readout). 2 barriers per accept
// (read-fence + write-fence; races proven fatal by m152-style lessons).
__global__ __launch_bounds__(256, 1) void scan_kernel(
    const int* __restrict__ x, const float* __restrict__ Htab,
    const float* __restrict__ Ktab, const float* __restrict__ Vtab,
    const float* __restrict__ nvtab,
    const float* __restrict__ Wq, const float* __restrict__ Wr,
    const float* __restrict__ alpha, const float* __restrict__ Wout,
    const float* __restrict__ bout, float* __restrict__ out)
{
  __shared__ float4 Kl4[VOCABN * H / 4];   // khat [c][j]; becomes M_N after scan
  __shared__ float4 Vl4[VOCABN * H / 4];   // v [c][i];   becomes M_T after scan
  __shared__ float4 Gl4[VOCABN * H / 4];   // Gram [c][cc] (static after init)
  __shared__ float4 Rl4[VOCABN * H / 4];   // residual [c][i]
  __shared__ int4   xl4[LSEQ / 4];
  __shared__ float  thl[VOCABN];           // 0.4*||v||
  __shared__ float  hbuf[H];
  __shared__ float  qbuf[H];
  __shared__ float  mbuf[H];
  float* Kl = (float*)Kl4;
  float* Vl = (float*)Vl4;
  float* Gl = (float*)Gl4;
  float* Rl = (float*)Rl4;
  int*   xl = (int*)xl4;

  const int b    = blockIdx.x;
  const int tid  = threadIdx.x;
  const int lane = tid & 63;
  const int wid  = tid >> 6;

  // ---- stage tables + token row into LDS (256 threads) ----
  {
    const float4* Kg = (const float4*)Ktab;
    const float4* Vg = (const float4*)Vtab;
    for (int q = tid; q < VOCABN * H / 4; q += 256) {
      float4 vq = Vg[q];
      Kl4[q] = Kg[q]; Vl4[q] = vq; Rl4[q] = vq;   // R init = v (M = 0)
    }
    const int4* xg = (const int4*)(x + b * LSEQ);
    for (int q = tid; q < LSEQ / 4; q += 256) xl4[q] = xg[q];
    if (tid < VOCABN) thl[tid] = nvtab[tid];
  }
  __syncthreads();

  // ---- Gram in LDS, rows split across waves (verbatim rounds 10-12) ----
  {
    float4 kr[16];
#pragma unroll
    for (int q = 0; q < 16; ++q) kr[q] = Kl4[lane * 16 + q];
    for (int r = 0; r < 16; ++r) {
      const int c2 = wid * 16 + r;
      const float4* kp2 = (const float4*)(Kl + c2 * H);
      float a0 = 0.f, a1 = 0.f, a2 = 0.f, a3 = 0.f;
#pragma unroll
      for (int q = 0; q < 16; ++q) {
        float4 kq = kp2[q];
        a0 = fmaf(kr[q].x, kq.x, a0);
        a1 = fmaf(kr[q].y, kq.y, a1);
        a2 = fmaf(kr[q].z, kq.z, a2);
        a3 = fmaf(kr[q].w, kq.w, a3);
      }
      Gl[c2 * H + lane] = (a0 + a1) + (a2 + a3);
    }
  }
  __syncthreads();

  // M column slice: Mw[q] holds M[lane][wid*16 + 4q .. 4q+3]
  float4 Mw[4];
#pragma unroll
  for (int q = 0; q < 4; ++q) Mw[q] = make_float4(0.f, 0.f, 0.f, 0.f);

  // depth-2 pipeline state
  int   c0 = xl[0], c1 = xl[1];
  float rv  = Rl[c0 * H + lane];
  float rvn = Rl[c1 * H + lane];
  float th0 = thl[c0], th1 = thl[c1];

  for (int t = 0; t < LSEQ; ++t) {
    const int ix2 = (t + 2 < LSEQ) ? t + 2 : LSEQ - 1;
    const int c2  = xl[ix2];
    float rb2  = Rl[c2 * H + lane];     // safe: last accept's write-fence passed
    float th2v = thl[c2];
    float g01  = Gl[c0 * H + c1];       // Gram is static -> race-free speculative reads
    float g02  = Gl[c0 * H + c2];

    float nd2 = reduce_to_lane63(rv * rv);
    float nds = sqrtf(__int_as_float(__builtin_amdgcn_readlane(__float_as_int(nd2), 63)));
    float thu = __int_as_float(__builtin_amdgcn_readfirstlane(__float_as_int(th0)));

    if (nds > thu) {                    // block-uniform (identical data per wave)
      const float delta = rv;
      // in-register forwarding (bitwise == the LDS RMW results below)
      rvn = fmaf(-g01, delta, rvn);
      rb2 = fmaf(-g02, delta, rb2);
      __syncthreads();                  // read-fence: all waves' top-of-step reads done
      // G row slice as 4 broadcast b128
      const float4* gp = ((const float4*)(Gl + c0 * H)) + wid * 4;
      float4 ga = gp[0], gb = gp[1], gc = gp[2], gd = gp[3];
      float gs[16] = {ga.x, ga.y, ga.z, ga.w, gb.x, gb.y, gb.z, gb.w,
                      gc.x, gc.y, gc.z, gc.w, gd.x, gd.y, gd.z, gd.w};
      // RMW 16 rows/wave (stride-1, conflict-free)
#pragma unroll
      for (int r = 0; r < 16; ++r) {
        const int cc = wid * 16 + r;
        Rl[cc * H + lane] = fmaf(-gs[r], delta, Rl[cc * H + lane]);
      }
      // M column slice (16 FMA + 4 broadcast b128)
      const float4* kp = ((const float4*)(Kl + c0 * H)) + wid * 4;
#pragma unroll
      for (int q = 0; q < 4; ++q) {
        float4 k4 = kp[q];
        Mw[q].x = fmaf(delta, k4.x, Mw[q].x);
        Mw[q].y = fmaf(delta, k4.y, Mw[q].y);
        Mw[q].z = fmaf(delta, k4.z, Mw[q].z);
        Mw[q].w = fmaf(delta, k4.w, Mw[q].w);
      }
      __syncthreads();                  // write-fence: visible before next prefetch
    }
    rv = rvn; rvn = rb2; c0 = c1; c1 = c2; th0 = th1; th1 = th2v;
  }

  // ---- reassemble M into LDS: Vl = M_T (conflict-free), Kl = M_N (verbatim round 12) ----
  __syncthreads();
#pragma unroll
  for (int r = 0; r < 4; ++r) {
    const int jb = wid * 16 + r * 4;
    float4 m = Mw[r];
    Vl[(jb + 0) * H + lane] = m.x;
    Vl[(jb + 1) * H + lane] = m.y;
    Vl[(jb + 2) * H + lane] = m.z;
    Vl[(jb + 3) * H + lane] = m.w;
    Kl[lane * H + jb + 0] = m.x;
    Kl[lane * H + jb + 1] = m.y;
    Kl[lane * H + jb + 2] = m.z;
    Kl[lane * H + jb + 3] = m.w;
  }
  __syncthreads();

  // ---------------- fused readout: wave 0 (M from LDS; verbatim round 12, passed) ----------------
  if (wid == 0) {
    const int clast = xl[LSEQ - 1];
    hbuf[lane] = Htab[clast * H + lane];

    float qi = 0.f;
    for (int j = 0; j < H; ++j) qi = fmaf(Wq[lane * H + j], hbuf[j], qi);
    qbuf[lane] = qi;

    float qri = 0.f;
    for (int j = 0; j < H; ++j) qri = fmaf(Wr[lane * H + j], qbuf[j], qri);

    // slot norms^2: lane s reads M_N column s (conflict-free)
    float n2 = 0.f;
    for (int i2 = 0; i2 < H; ++i2) { float m = Kl[i2 * H + lane]; n2 = fmaf(m, m, n2); }

    // top-8 slots by norm (ties -> smaller index)
    const int KS = 8;
    int idxs[KS];
    float nloc = n2;
#pragma unroll
    for (int k = 0; k < KS; ++k) {
      float v = nloc; int idx = lane;
#pragma unroll
      for (int s = 1; s < 64; s <<= 1) {
        float ov = __shfl_xor(v, s, 64);
        int   oi = __shfl_xor(idx, s, 64);
        if (ov > v || (ov == v && oi < idx)) { v = ov; idx = oi; }
      }
      idxs[k] = idx;
      if (lane == idx) nloc = -1.f;
    }

    float sel[KS], lg[KS];
#pragma unroll
    for (int k = 0; k < KS; ++k) {
      float s = Vl[idxs[k] * H + lane];     // M_T[idx][lane]
      sel[k] = s;
      lg[k] = wave_allsum(s * qri) * 0.125f;   // / sqrt(64)
    }
    float lmax = lg[0];
#pragma unroll
    for (int k = 1; k < KS; ++k) lmax = fmaxf(lmax, lg[k]);
    float esum = 0.f, retro = 0.f;
#pragma unroll
    for (int k = 0; k < KS; ++k) {
      float e = expf(lg[k] - lmax);
      esum += e;
      retro = fmaf(e, sel[k], retro);
    }
    retro /= esum;

    // m_ctx = M q : lane i, ascending j reading M_T[j][lane] (conflict-free)
    float mc = 0.f;
    for (int j = 0; j < H; ++j) mc = fmaf(Vl[j * H + lane], qbuf[j], mc);

    float a = 1.f / (1.f + expf(-alpha[0]));
    float mixed = fmaxf(fmaf(a, retro, (1.f - a) * mc), 0.f);
    mbuf[lane] = mixed;

    float oo = bout[lane];
    for (int i2 = 0; i2 < H; ++i2) oo = fmaf(Wout[lane * H + i2], mbuf[i2], oo);
    out[b * VOCABN + lane] = oo;
  }
}

extern "C" void kernel_launch(void* const* d_in, const int* in_sizes, int n_in,
                              void* d_out, int out_size, void* d_ws, size_t ws_size,
                              hipStream_t stream) {
  const int*   x     = (const int*)d_in[0];
  const float* embed = (const float*)d_in[1];
  const float* W1    = (const float*)d_in[2];
  const float* b1    = (const float*)d_in[3];
  const float* W2    = (const float*)d_in[4];
  const float* b2    = (const float*)d_in[5];
  const float* ln_g  = (const float*)d_in[6];
  const float* ln_b  = (const float*)d_in[7];
  const float* Wk    = (const float*)d_in[8];
  const float* Wv    = (const float*)d_in[9];
  const float* Wq    = (const float*)d_in[10];
  const float* Wr    = (const float*)d_in[11];
  const float* alpha = (const float*)d_in[12];
  const float* Wout  = (const float*)d_in[13];
  const float* bout  = (const float*)d_in[14];
  float* out = (float*)d_out;

  const int B = in_sizes[0] / LSEQ;

  float* ws    = (float*)d_ws;
  float* Htab  = ws;          // 4096
  float* Ktab  = ws + 4096;   // 4096
  float* Vtab  = ws + 8192;   // 4096
  float* nvtab = ws + 12288;  // 64

  tables_kernel<<<VOCABN, 64, 0, stream>>>(embed, W1, b1, W2, b2, ln_g, ln_b,
                                           Wk, Wv, Htab, Ktab, Vtab, nvtab);
  scan_kernel<<<B, 256, 0, stream>>>(x, Htab, Ktab, Vtab, nvtab,
                                     Wq, Wr, alpha, Wout, bout, out);
}